// Round 2
// baseline (955.456 us; speedup 1.0000x reference)
//
#include <hip/hip_runtime.h>
#include <math.h>

#define N_NODES   100000
#define N_FEAT    512
#define HIDDEN    16
#define N_CLASSES 7
#define N_EDGES   3200000

// bucket = dst >> 7  (128 nodes per bucket)
#define BSHIFT 7
#define BNODES 128
#define BMASK  127
#define NBUK   782            // ceil(100000/128)
#define CHUNK  16384
#define NCHUNK 196            // ceil(3200000/16384)

// ---------- bucket histogram / scan / scatter (counting sort by dst bucket) ----------

__global__ void k_zero_b(int* __restrict__ btot) {
    int i = threadIdx.x;
    if (i < NBUK) btot[i] = 0;
}

__global__ __launch_bounds__(256) void k_bhist(const int* __restrict__ dst,
                                               int* __restrict__ btot) {
    __shared__ int h[NBUK];
    int tid = threadIdx.x;
    for (int i = tid; i < NBUK; i += 256) h[i] = 0;
    __syncthreads();
    int base = blockIdx.x * CHUNK;
    for (int i = tid; i < CHUNK; i += 256) {
        int e = base + i;
        if (e < N_EDGES) atomicAdd(&h[dst[e] >> BSHIFT], 1);
    }
    __syncthreads();
    for (int i = tid; i < NBUK; i += 256)
        if (h[i]) atomicAdd(&btot[i], h[i]);
}

__global__ void k_bscan(const int* __restrict__ btot, int* __restrict__ gbase,
                        int* __restrict__ gcur) {
    __shared__ int sd[1024];
    int t = threadIdx.x;
    int v = (t < NBUK) ? btot[t] : 0;
    sd[t] = v;
    __syncthreads();
    for (int off = 1; off < 1024; off <<= 1) {
        int a = (t >= off) ? sd[t - off] : 0;
        __syncthreads();
        sd[t] += a;
        __syncthreads();
    }
    if (t < NBUK) {
        int ex = sd[t] - v;  // exclusive
        gbase[t] = ex;
        gcur[t]  = ex;
    }
}

__global__ __launch_bounds__(256) void k_bscatter(const int* __restrict__ src,
                                                  const int* __restrict__ dst,
                                                  int* __restrict__ gcur,
                                                  int* __restrict__ entries) {
    __shared__ int h[NBUK];
    __shared__ int lb[NBUK];
    int tid = threadIdx.x;
    for (int i = tid; i < NBUK; i += 256) h[i] = 0;
    __syncthreads();
    int base = blockIdx.x * CHUNK;
    for (int i = tid; i < CHUNK; i += 256) {
        int e = base + i;
        if (e < N_EDGES) atomicAdd(&h[dst[e] >> BSHIFT], 1);
    }
    __syncthreads();
    for (int i = tid; i < NBUK; i += 256) {
        int c = h[i];
        lb[i] = c ? atomicAdd(&gcur[i], c) : 0;
        h[i] = 0;  // reuse as local cursor
    }
    __syncthreads();
    for (int i = tid; i < CHUNK; i += 256) {
        int e = base + i;
        if (e < N_EDGES) {
            int d = dst[e];
            int b = d >> BSHIFT;
            int pos = lb[b] + atomicAdd(&h[b], 1);
            entries[pos] = src[e] | ((d & BMASK) << 17);  // src<2^17, loc 7 bits
        }
    }
}

// ---------- per-node dinv from bucket entries ----------

__global__ __launch_bounds__(256) void k_dinv(const int* __restrict__ entries,
                                              const int* __restrict__ btot,
                                              const int* __restrict__ gbase,
                                              float* __restrict__ dinv) {
    __shared__ int c[BNODES];
    int tid = threadIdx.x;
    if (tid < BNODES) c[tid] = 0;
    __syncthreads();
    int bk = blockIdx.x;
    int cnt = btot[bk], base = gbase[bk];
    for (int i = tid; i < cnt; i += 256)
        atomicAdd(&c[entries[base + i] >> 17], 1);
    __syncthreads();
    if (tid < BNODES) {
        int n = bk * BNODES + tid;
        if (n < N_NODES) dinv[n] = rsqrtf((float)(c[tid] + 1));  // +1 self-loop
    }
}

// ---------- GEMM1: hs1 = dinv ⊙ (x @ W1), 16 lanes per row ----------

__global__ __launch_bounds__(256) void k_gemm1(const float* __restrict__ x,
                                               const float* __restrict__ W1,
                                               const float* __restrict__ dinv,
                                               float* __restrict__ hs1) {
    __shared__ float wl[512 * 17];
    int tid = threadIdx.x;
    for (int idx = tid; idx < N_FEAT * HIDDEN; idx += 256) {
        int col = idx >> 4, o = idx & 15;
        wl[col * 17 + o] = W1[idx];
    }
    __syncthreads();

    int lane = tid & 15;
    int row  = blockIdx.x * 16 + (tid >> 4);
    const float4* xr = (const float4*)(x + (size_t)row * N_FEAT);

    float acc[16];
#pragma unroll
    for (int o = 0; o < 16; o++) acc[o] = 0.f;

#pragma unroll
    for (int i = 0; i < 8; i++) {
        int col = i * 64 + lane * 4;
        float4 xv = xr[col >> 2];
#pragma unroll
        for (int j = 0; j < 4; j++) {
            float xj = (&xv.x)[j];
            const float* wr = &wl[(col + j) * 17];
#pragma unroll
            for (int o = 0; o < 16; o++) acc[o] += xj * wr[o];
        }
    }

#pragma unroll
    for (int m = 1; m < 16; m <<= 1) {
#pragma unroll
        for (int o = 0; o < 16; o++) acc[o] += __shfl_xor(acc[o], m, 64);
    }

    if (lane == 0) {
        float dn = dinv[row];
        float4* outp = (float4*)(hs1 + (size_t)row * 16);
        outp[0] = make_float4(acc[0] * dn, acc[1] * dn, acc[2] * dn, acc[3] * dn);
        outp[1] = make_float4(acc[4] * dn, acc[5] * dn, acc[6] * dn, acc[7] * dn);
        outp[2] = make_float4(acc[8] * dn, acc[9] * dn, acc[10] * dn, acc[11] * dn);
        outp[3] = make_float4(acc[12] * dn, acc[13] * dn, acc[14] * dn, acc[15] * dn);
    }
}

// ---------- layer1 aggregate + bias + relu + W2 transform: hs2 = dinv ⊙ (relu(...)@W2) ----------

__global__ __launch_bounds__(256) void k_bagg1(const float* __restrict__ hs1,
                                               const int* __restrict__ entries,
                                               const int* __restrict__ btot,
                                               const int* __restrict__ gbase,
                                               const float* __restrict__ dinv,
                                               const float* __restrict__ b1,
                                               const float* __restrict__ W2,
                                               float* __restrict__ hs2) {
    __shared__ float acc[BNODES * 17];  // pitch 17: bank-conflict-free-ish
    __shared__ float w2l[HIDDEN * N_CLASSES];
    int tid = threadIdx.x;
    if (tid < HIDDEN * N_CLASSES) w2l[tid] = W2[tid];
    for (int i = tid; i < BNODES * 17; i += 256) acc[i] = 0.f;
    __syncthreads();

    int bk = blockIdx.x;
    int cnt = btot[bk], base = gbase[bk];
    int lane = tid & 15;
    int eg   = tid >> 4;  // 16 edges in flight per block

    int e = eg;
    for (; e + 16 < cnt; e += 32) {
        int en0 = entries[base + e];
        int en1 = entries[base + e + 16];
        float v0 = hs1[(size_t)(en0 & 0x1FFFF) * 16 + lane];
        float v1 = hs1[(size_t)(en1 & 0x1FFFF) * 16 + lane];
        atomicAdd(&acc[(en0 >> 17) * 17 + lane], v0);
        atomicAdd(&acc[(en1 >> 17) * 17 + lane], v1);
    }
    if (e < cnt) {
        int en = entries[base + e];
        float v = hs1[(size_t)(en & 0x1FFFF) * 16 + lane];
        atomicAdd(&acc[(en >> 17) * 17 + lane], v);
    }
    __syncthreads();

    if (tid < BNODES) {
        int n = bk * BNODES + tid;
        if (n < N_NODES) {
            float dn = dinv[n];
            const float4* hp = (const float4*)(hs1 + (size_t)n * 16);
            float4 s0 = hp[0], s1 = hp[1], s2 = hp[2], s3 = hp[3];
            float self[16] = {s0.x, s0.y, s0.z, s0.w, s1.x, s1.y, s1.z, s1.w,
                              s2.x, s2.y, s2.z, s2.w, s3.x, s3.y, s3.z, s3.w};
            float z[16];
#pragma unroll
            for (int k = 0; k < 16; k++)
                z[k] = fmaxf(dn * (acc[tid * 17 + k] + self[k]) + b1[k], 0.f);
            float t[7];
#pragma unroll
            for (int j = 0; j < 7; j++) t[j] = 0.f;
#pragma unroll
            for (int k = 0; k < 16; k++) {
#pragma unroll
                for (int j = 0; j < 7; j++) t[j] += z[k] * w2l[k * 7 + j];
            }
            float4* o = (float4*)(hs2 + (size_t)n * 8);
            o[0] = make_float4(dn * t[0], dn * t[1], dn * t[2], dn * t[3]);
            o[1] = make_float4(dn * t[4], dn * t[5], dn * t[6], 0.f);
        }
    }
}

// ---------- layer2 aggregate + bias + log_softmax ----------

__global__ __launch_bounds__(256) void k_bagg2(const float* __restrict__ hs2,
                                               const int* __restrict__ entries,
                                               const int* __restrict__ btot,
                                               const int* __restrict__ gbase,
                                               const float* __restrict__ dinv,
                                               const float* __restrict__ b2,
                                               float* __restrict__ out) {
    __shared__ float acc[BNODES * 9];  // pitch 9
    int tid = threadIdx.x;
    for (int i = tid; i < BNODES * 9; i += 256) acc[i] = 0.f;
    __syncthreads();

    int bk = blockIdx.x;
    int cnt = btot[bk], base = gbase[bk];
    int lane = tid & 7;
    int eg   = tid >> 3;  // 32 edges in flight

    int e = eg;
    for (; e + 32 < cnt; e += 64) {
        int en0 = entries[base + e];
        int en1 = entries[base + e + 32];
        float v0 = hs2[(size_t)(en0 & 0x1FFFF) * 8 + lane];
        float v1 = hs2[(size_t)(en1 & 0x1FFFF) * 8 + lane];
        atomicAdd(&acc[(en0 >> 17) * 9 + lane], v0);
        atomicAdd(&acc[(en1 >> 17) * 9 + lane], v1);
    }
    if (e < cnt) {
        int en = entries[base + e];
        float v = hs2[(size_t)(en & 0x1FFFF) * 8 + lane];
        atomicAdd(&acc[(en >> 17) * 9 + lane], v);
    }
    __syncthreads();

    if (tid < BNODES) {
        int n = bk * BNODES + tid;
        if (n < N_NODES) {
            float dn = dinv[n];
            const float4* hp = (const float4*)(hs2 + (size_t)n * 8);
            float4 s0 = hp[0], s1 = hp[1];
            float self[7] = {s0.x, s0.y, s0.z, s0.w, s1.x, s1.y, s1.z};
            float l[7];
#pragma unroll
            for (int j = 0; j < 7; j++)
                l[j] = dn * (acc[tid * 9 + j] + self[j]) + b2[j];
            float m = l[0];
#pragma unroll
            for (int j = 1; j < 7; j++) m = fmaxf(m, l[j]);
            float s = 0.f;
#pragma unroll
            for (int j = 0; j < 7; j++) s += expf(l[j] - m);
            float ls = m + logf(s);
            float* op = out + (size_t)n * 7;
#pragma unroll
            for (int j = 0; j < 7; j++) op[j] = l[j] - ls;
        }
    }
}

// ---------- launch ----------

extern "C" void kernel_launch(void* const* d_in, const int* in_sizes, int n_in,
                              void* d_out, int out_size, void* d_ws, size_t ws_size,
                              hipStream_t stream) {
    const float* x  = (const float*)d_in[0];
    const int*   ei = (const int*)d_in[1];
    const float* W1 = (const float*)d_in[2];
    const float* b1 = (const float*)d_in[3];
    const float* W2 = (const float*)d_in[4];
    const float* b2 = (const float*)d_in[5];
    float* out = (float*)d_out;

    const int* src = ei;
    const int* dst = ei + N_EDGES;

    char* w = (char*)d_ws;
    int*   btot    = (int*)(w + 0);           //  3128 B
    int*   gbase   = (int*)(w + 3200);        //  3128 B
    int*   gcur    = (int*)(w + 6400);        //  3128 B
    float* dinv    = (float*)(w + 9600);      //  400000 B
    float* hs1     = (float*)(w + 409600);    //  6.4 MB
    float* hs2     = (float*)(w + 6809600);   //  3.2 MB
    int*   entries = (int*)(w + 10009600);    //  12.8 MB  (total ~22.8 MB)

    k_zero_b  <<<1, 1024, 0, stream>>>(btot);
    k_bhist   <<<NCHUNK, 256, 0, stream>>>(dst, btot);
    k_bscan   <<<1, 1024, 0, stream>>>(btot, gbase, gcur);
    k_bscatter<<<NCHUNK, 256, 0, stream>>>(src, dst, gcur, entries);
    k_dinv    <<<NBUK, 256, 0, stream>>>(entries, btot, gbase, dinv);
    k_gemm1   <<<N_NODES / 16, 256, 0, stream>>>(x, W1, dinv, hs1);
    k_bagg1   <<<NBUK, 256, 0, stream>>>(hs1, entries, btot, gbase, dinv, b1, W2, hs2);
    k_bagg2   <<<NBUK, 256, 0, stream>>>(hs2, entries, btot, gbase, dinv, b2, out);
}